// Round 5
// baseline (1217.758 us; speedup 1.0000x reference)
//
#include <hip/hip_runtime.h>

typedef unsigned short ushort_t;
typedef __attribute__((ext_vector_type(8))) short   short8_t;
typedef __attribute__((ext_vector_type(4))) float   float4_t;
typedef __attribute__((ext_vector_type(4))) unsigned short ushort4_t;

__device__ __forceinline__ ushort_t f2b(float f) {
    unsigned int u = __float_as_uint(f);
    u += 0x7FFFu + ((u >> 16) & 1u);      // round-to-nearest-even
    return (ushort_t)(u >> 16);
}
__device__ __forceinline__ float b2f(ushort_t s) {
    return __uint_as_float(((unsigned int)s) << 16);
}
__device__ __forceinline__ float frcp(float x) { return __builtin_amdgcn_rcpf(x); }
__device__ __forceinline__ float sigf(float x) { return frcp(1.f + __expf(-x)); }
__device__ __forceinline__ float tanhf_fast(float x) {
    return 1.f - 2.f * frcp(__expf(2.f * x) + 1.f);
}

// ---------------- weight convert: fp32 -> bf16 fragment-order ----------------
// Fragment order: for (m, tn=col-tile/16, kf) the 64 lanes' short8 B-fragments
// stored contiguously (lane*8 ushorts). Lane frag: col = tn*16 + (lane&15),
// k = kf*32 + (lane>>4)*8 + j. Hot-kernel loads become base + lane*16B.
// ws (ushort): [0,196608): rec frags ((m*16+tn)*8+kf)*512 + lane*8 + j
//              [196608, 344064): in frags ((m*16+tn)*6+kf)*512 + lane*8 + j
__global__ void cvt_w(const float* __restrict__ ffr, const float* __restrict__ gr,
                      const float* __restrict__ tr,  const float* __restrict__ ffi,
                      const float* __restrict__ gi,  const float* __restrict__ ti,
                      ushort_t* __restrict__ o)
{
    int i = blockIdx.x * 256 + threadIdx.x;   // exactly [0, 344064)
    float v;
    if (i < 196608) {
        int j    = i & 7;
        int lane = (i >> 3) & 63;
        int kf   = (i >> 9) & 7;
        int tn   = (i >> 12) & 15;
        int m    = i >> 16;
        int col  = tn*16 + (lane & 15);
        int k    = kf*32 + (lane >> 4)*8 + j;
        const float* W = (m == 0) ? ffr : (m == 1) ? gr : tr;
        v = W[(col << 8) + k];
    } else {
        int f    = i - 196608;
        int j    = f & 7;
        int lane = (f >> 3) & 63;
        int q    = f >> 9;            // [0,288) = (m*16+tn)*6+kf
        int kf   = q % 6;
        int tt   = q / 6;
        int tn   = tt & 15;
        int m    = tt >> 4;
        int col  = tn*16 + (lane & 15);
        int k    = kf*32 + (lane >> 4)*8 + j;
        const float* W = (m == 0) ? ffi : (m == 1) ? gi : ti;
        v = W[col*192 + k];
    }
    o[i] = f2b(v);
}

// ---------------- fused LTC kernel ----------------
// 256 blocks x 1024 thr (16 waves), 1 block/CU, 4 waves/SIMD. Block owns 16
// batch rows; wave wv owns hidden col-tile tn=wv (16 cols). Rec weights
// m=0,1 resident (64 VGPRs/wave); m=2 streamed coalesced from L2 per step.
// Proj: two t-pair passes (pac[3][2]) to cap live regs ~115 < 128.
// Hb: 2 x 4224 el ([16 rows][264]). One barrier per step; x-staging for
// chunk tc+1 folded into steps 0..2 (1 float4/thread/step).
__global__ __launch_bounds__(1024, 4) void ltc_fused(
    const float* __restrict__ x,
    const ushort_t* __restrict__ wbf,
    const float* __restrict__ ff_in_b, const float* __restrict__ ff_bias,
    const float* __restrict__ g_in_b,  const float* __restrict__ g_bias,
    const float* __restrict__ t_in_b,  const float* __restrict__ t_bias,
    const float* __restrict__ head_w,  const float* __restrict__ head_b,
    float* __restrict__ out)
{
    __shared__ __align__(16) ushort_t smem[70400];
    ushort_t* Al = smem;                 // 12800 el
    ushort_t* Pl = smem + 12800;         // 49152 el: [4t][16wv][3m][256]
    ushort_t* Hb = smem + 61952;         // 8448 el = 2 x 4224

    const int tid   = threadIdx.x;
    const int lane  = tid & 63;
    const int wv    = tid >> 6;          // 0..15 = col-tile
    const int l16   = lane & 15;
    const int l4    = lane >> 4;
    const int bbase = blockIdx.x << 4;

    const ushort_t* recF = wbf;
    const ushort_t* inF  = wbf + 196608;

    const int col = wv*16 + l16;         // this lane's hidden col

    // resident rec-weight B-fragments for m=0,1 (coalesced: base + lane*16B)
    short8_t wr[2][8];                   // 64 VGPRs
#pragma unroll
    for (int m = 0; m < 2; ++m)
#pragma unroll
        for (int k = 0; k < 8; ++k)
            wr[m][k] = *(const short8_t*)(
                recF + (((m*16 + wv)*8 + k) << 9) + lane*8);

    const float bs0 = ff_in_b[col] + ff_bias[col];
    const float bs1 = g_in_b[col]  + g_bias[col];
    const float bs2 = t_in_b[col]  + t_bias[col];

    float hp[4];
#pragma unroll
    for (int r = 0; r < 4; ++r) hp[r] = 0.f;

    for (int i = tid; i < 4224; i += 1024) Hb[i] = 0;   // h0 = 0 (buffer 0)

    // stage chunk 0 into Al
#pragma unroll 1
    for (int p = 0; p < 3; ++p) {
        int flat = p*1024 + tid;              // [0,3072) float4s
        int w4   = flat & 15;
        int tt   = (flat >> 4) & 3;
        int rest = flat >> 6;                 // b*3 + c
        int c = rest % 3;
        int b = rest / 3;
        const float4_t v = *(const float4_t*)(
            x + (((bbase + b)*3 + c)*4096) + tt*64 + (w4 << 2));
        ushort4_t o;
        o.x = f2b(v.x); o.y = f2b(v.y); o.z = f2b(v.z); o.w = f2b(v.w);
        *(ushort4_t*)(Al + tt*3200 + b*200 + (c << 6) + (w4 << 2)) = o;
    }
    __syncthreads();

#pragma unroll 1
    for (int tc = 0; tc < 16; ++tc) {
        // ======== input projection, two t-pair passes (caps live registers)
#pragma unroll 1
        for (int tp = 0; tp < 2; ++tp) {
            float4_t pac[3][2];
#pragma unroll
            for (int tt = 0; tt < 2; ++tt) {
                pac[0][tt] = (float4_t){bs0, bs0, bs0, bs0};
                pac[1][tt] = (float4_t){bs1, bs1, bs1, bs1};
                pac[2][tt] = (float4_t){bs2, bs2, bs2, bs2};
            }
            const ushort_t* wcb = inF + lane*8;
#pragma unroll
            for (int kf = 0; kf < 6; ++kf) {
                const short8_t bk0 = *(const short8_t*)(wcb + (((     wv)*6 + kf) << 9));
                const short8_t bk1 = *(const short8_t*)(wcb + (((16 + wv)*6 + kf) << 9));
                const short8_t bk2 = *(const short8_t*)(wcb + (((32 + wv)*6 + kf) << 9));
#pragma unroll
                for (int tt = 0; tt < 2; ++tt) {
                    const int t = tp*2 + tt;
                    const short8_t a = *(const short8_t*)(
                        Al + t*3200 + l16*200 + kf*32 + l4*8);
                    pac[0][tt] = __builtin_amdgcn_mfma_f32_16x16x32_bf16(a, bk0, pac[0][tt], 0, 0, 0);
                    pac[1][tt] = __builtin_amdgcn_mfma_f32_16x16x32_bf16(a, bk1, pac[1][tt], 0, 0, 0);
                    pac[2][tt] = __builtin_amdgcn_mfma_f32_16x16x32_bf16(a, bk2, pac[2][tt], 0, 0, 0);
                }
            }
#pragma unroll
            for (int m = 0; m < 3; ++m)
#pragma unroll
                for (int tt = 0; tt < 2; ++tt) {
                    const int t = tp*2 + tt;
                    ushort4_t o;
                    o.x = f2b(pac[m][tt].x); o.y = f2b(pac[m][tt].y);
                    o.z = f2b(pac[m][tt].z); o.w = f2b(pac[m][tt].w);
                    *(ushort4_t*)(Pl + (((t*16 + wv)*3 + m) << 8) + (lane << 2)) = o;
                }
        }

        // ======== 4 recurrent steps (1 barrier each)
#pragma unroll 1
        for (int t = 0; t < 4; ++t) {
            const int step = tc*4 + t;
            const int cur = step & 1;
            const int nxt = cur ^ 1;

            __syncthreads();

            // -- issue staging load early (hidden under MFMA)
            const bool do_stage = (t < 3) && (tc < 15);
            float4_t sv;
            int sa = 0;
            if (do_stage) {
                int flat = t*1024 + tid;          // [0,3072)
                int w4   = flat & 15;
                int tt   = (flat >> 4) & 3;
                int rest = flat >> 6;
                int c = rest % 3;
                int b = rest / 3;
                sv = *(const float4_t*)(
                    x + (((bbase + b)*3 + c)*4096) + ((tc + 1)*4 + tt)*64 + (w4 << 2));
                sa = tt*3200 + b*200 + (c << 6) + (w4 << 2);
            }

            // -- stream all m=2 rec fragments (coalesced, L2-resident)
            short8_t s2[8];
#pragma unroll
            for (int k = 0; k < 8; ++k)
                s2[k] = *(const short8_t*)(
                    recF + (((32 + wv)*8 + k) << 9) + lane*8);

            // -- init acc from Pl (own-lane, no barrier needed)
            float4_t acc[3];
#pragma unroll
            for (int m = 0; m < 3; ++m) {
                const ushort4_t p = *(const ushort4_t*)(
                    Pl + (((t*16 + wv)*3 + m) << 8) + (lane << 2));
                acc[m] = (float4_t){b2f(p.x), b2f(p.y), b2f(p.z), b2f(p.w)};
            }

            // -- K loop: A from Hb (shared), B resident/streamed
#pragma unroll
            for (int kk = 0; kk < 8; ++kk) {
                const short8_t a = *(const short8_t*)(
                    Hb + cur*4224 + l16*264 + kk*32 + l4*8);
                acc[0] = __builtin_amdgcn_mfma_f32_16x16x32_bf16(a, wr[0][kk], acc[0], 0, 0, 0);
                acc[1] = __builtin_amdgcn_mfma_f32_16x16x32_bf16(a, wr[1][kk], acc[1], 0, 0, 0);
                acc[2] = __builtin_amdgcn_mfma_f32_16x16x32_bf16(a, s2[kk],    acc[2], 0, 0, 0);
            }

            // -- finish staging write to Al
            if (do_stage) {
                ushort4_t o;
                o.x = f2b(sv.x); o.y = f2b(sv.y); o.z = f2b(sv.z); o.w = f2b(sv.w);
                *(ushort4_t*)(Al + sa) = o;
            }

            // -- epilogue: C element (row=l4*4+r [batch], col [hidden])
#pragma unroll
            for (int r = 0; r < 4; ++r) {
                const float h   = hp[r];
                const float cd  = tanhf_fast(acc[0][r]);
                const float g   = sigf(acc[1][r]);
                const float tau = 0.5f + 1.5f * sigf(acc[2][r]);
                const float hn  = tanhf_fast(h + (g*cd - h) * frcp(tau));
                hp[r] = hn;
                Hb[nxt*4224 + (l4*4 + r)*264 + col] = f2b(hn);
            }
        }
    }
    __syncthreads();

    // ---- head: out[b,o] = sum_j h[b,j]*head_w[o,j] + head_b[o]
    float* hf = (float*)(smem + 12800);      // [16][257] fp32, reuse Pl space
#pragma unroll
    for (int r = 0; r < 4; ++r)
        hf[(l4*4 + r)*257 + col] = hp[r];
    __syncthreads();
    if (tid < 160) {
        const int r = tid / 10;
        const int o = tid - r*10;
        float s = head_b[o];
        const float* wrow = head_w + o*256;
        const float* hrow = hf + r*257;
#pragma unroll 8
        for (int j = 0; j < 256; ++j) s += hrow[j] * wrow[j];
        out[bbase*10 + tid] = s;
    }
}

extern "C" void kernel_launch(void* const* d_in, const int* in_sizes, int n_in,
                              void* d_out, int out_size, void* d_ws, size_t ws_size,
                              hipStream_t stream)
{
    const float* x     = (const float*)d_in[0];
    const float* ffi_w = (const float*)d_in[1];
    const float* ffi_b = (const float*)d_in[2];
    const float* ffr_w = (const float*)d_in[3];
    const float* ff_bs = (const float*)d_in[4];
    const float* gi_w  = (const float*)d_in[5];
    const float* gi_b  = (const float*)d_in[6];
    const float* gr_w  = (const float*)d_in[7];
    const float* g_bs  = (const float*)d_in[8];
    const float* ti_w  = (const float*)d_in[9];
    const float* ti_b  = (const float*)d_in[10];
    const float* tr_w  = (const float*)d_in[11];
    const float* t_bs  = (const float*)d_in[12];
    const float* hw    = (const float*)d_in[13];
    const float* hb    = (const float*)d_in[14];

    ushort_t* ws = (ushort_t*)d_ws;   // needs 688128 bytes

    cvt_w<<<1344, 256, 0, stream>>>(ffr_w, gr_w, tr_w, ffi_w, gi_w, ti_w, ws);
    ltc_fused<<<256, 1024, 0, stream>>>(x, ws, ffi_b, ff_bs, gi_b, g_bs,
                                        ti_b, t_bs, hw, hb, (float*)d_out);
}